// Round 9
// baseline (548.800 us; speedup 1.0000x reference)
//
#include <hip/hip_runtime.h>
#include <hip/hip_bf16.h>

#define N_NODES 50000
#define N_EDGES 500000
#define N_FEAT 128
#define EMB_DIM 1024
#define HIDDEN 128
#define OUT_DIM 10
#define N_GRAPHS 64
#define NB_NODE 196   // ceil(N_NODES/256)

typedef __attribute__((ext_vector_type(8))) short short8;   // 8 bf16 = 4 VGPR (MFMA A/B frag)
typedef __attribute__((ext_vector_type(4))) float f32x4;    // MFMA C/D frag

// ---- fp32 -> bf16 RTN-even (finite inputs) ----
__device__ __forceinline__ unsigned short f2bf(float f) {
    unsigned int u = __float_as_uint(f);
    return (unsigned short)((u + 0x7fffu + ((u >> 16) & 1u)) >> 16);
}
// unpack a dword holding 2 bf16 (elements 2k, 2k+1); pack the inverse
__device__ __forceinline__ float bflo(unsigned int r) { return __uint_as_float(r << 16); }
__device__ __forceinline__ float bfhi(unsigned int r) { return __uint_as_float(r & 0xffff0000u); }
__device__ __forceinline__ unsigned int packbf(float lo, float hi) {
    return ((unsigned int)f2bf(hi) << 16) | f2bf(lo);
}

// ---------------- W (K x 128) -> Wt (128 x K) bf16 ----------------
__device__ __forceinline__ void prep_one(const float* __restrict__ W,
                                         unsigned short* __restrict__ Wt,
                                         int K, int t) {
    int n = t & 127;
    int c = t >> 7;
    if (c * 16 >= K) return;
    short8 h0, h1;
#pragma unroll
    for (int i = 0; i < 16; i++) {
        unsigned short h = f2bf(W[(size_t)(c * 16 + i) * HIDDEN + n]);
        if (i < 8) h0[i] = (short)h;
        else       h1[i - 8] = (short)h;
    }
    size_t o = (size_t)n * K + c * 16;
    *(short8*)&Wt[o] = h0;
    *(short8*)&Wt[o + 8] = h1;
}

// ------- init (dc=0, pool buffers=0) + weight prep, fused via block ranges ----------
// W1 needs 36 blocks (128 cols x 72 chunks); W2 needs 4 blocks (128 cols x 8 chunks).
__global__ __launch_bounds__(256) void k_init(unsigned long long* __restrict__ dc,
                                              float* __restrict__ sums,
                                              float* __restrict__ counts,
                                              const float* __restrict__ W1,
                                              unsigned short* __restrict__ Wt1,
                                              const float* __restrict__ W2,
                                              unsigned short* __restrict__ Wt2) {
    int b = blockIdx.x;
    if (b < NB_NODE) {
        int i = b * 256 + threadIdx.x;
        if (i < N_NODES) dc[i] = 0ULL;
        if (i < N_GRAPHS * HIDDEN) sums[i] = 0.0f;
        if (i < N_GRAPHS) counts[i] = 0.0f;
    } else if (b < NB_NODE + 36) {
        prep_one(W1, Wt1, N_FEAT + EMB_DIM, (b - NB_NODE) * 256 + threadIdx.x);
    } else {  // 4 blocks: 1024 threads for W2's 128x8 chunks
        prep_one(W2, Wt2, HIDDEN, (b - NB_NODE - 36) * 256 + threadIdx.x);
    }
}

// ------- degree scatter x4: ONE u64 atomic = (count<<32) | fixedpoint(ew, 2^24) -----
__global__ __launch_bounds__(256) void k_deg(const int* __restrict__ dst,
                                             const float* __restrict__ ew,
                                             unsigned long long* __restrict__ dc) {
    int e4 = blockIdx.x * 256 + threadIdx.x;
    if (e4 < N_EDGES / 4) {
        int4 d4 = ((const int4*)dst)[e4];
        float4 w4 = ((const float4*)ew)[e4];
        atomicAdd(&dc[d4.x], (1ULL << 32) | (unsigned long long)(unsigned int)(w4.x * 16777216.0f));
        atomicAdd(&dc[d4.y], (1ULL << 32) | (unsigned long long)(unsigned int)(w4.y * 16777216.0f));
        atomicAdd(&dc[d4.z], (1ULL << 32) | (unsigned long long)(unsigned int)(w4.z * 16777216.0f));
        atomicAdd(&dc[d4.w], (1ULL << 32) | (unsigned long long)(unsigned int)(w4.w * 16777216.0f));
    }
}

// ---------------- scan pass 1: per-block (256 nodes) reduce of counts ---------------
__global__ __launch_bounds__(256) void k_scan1(const unsigned long long* __restrict__ dc,
                                               int* __restrict__ bsum) {
    __shared__ int wsum[4];
    int i = blockIdx.x * 256 + threadIdx.x;
    int v = (i < N_NODES) ? (int)((const uint2*)dc)[i].y : 0;
#pragma unroll
    for (int off = 32; off; off >>= 1) v += __shfl_down(v, off, 64);
    if ((threadIdx.x & 63) == 0) wsum[threadIdx.x >> 6] = v;
    __syncthreads();
    if (threadIdx.x == 0) bsum[blockIdx.x] = wsum[0] + wsum[1] + wsum[2] + wsum[3];
}

// -- scan pass 2 (fused): each block rescans bsum in LDS, then per-node scan + dinv --
__global__ __launch_bounds__(256) void k_scan3(const unsigned long long* __restrict__ dc,
                                               const int* __restrict__ bsum,
                                               int* __restrict__ cursor,
                                               int* __restrict__ rowptr,
                                               float* __restrict__ dinv) {
    __shared__ int sb[256];
    __shared__ int sh[256];
    __shared__ int bofs_s;
    const int t = threadIdx.x;

    // block-sum exclusive scan (redundant per block; 784 B)
    int vb = (t < NB_NODE) ? bsum[t] : 0;
    sb[t] = vb;
    __syncthreads();
    for (int off = 1; off < 256; off <<= 1) {
        int add = (t >= off) ? sb[t - off] : 0;
        __syncthreads();
        sb[t] += add;
        __syncthreads();
    }
    if (t == blockIdx.x) bofs_s = sb[t] - vb;  // exclusive prefix at this block

    // per-node scan
    const int i = blockIdx.x * 256 + t;
    uint2 d = (i < N_NODES) ? ((const uint2*)dc)[i] : make_uint2(0u, 0u);
    int v = (int)d.y;
    sh[t] = v;
    __syncthreads();  // also publishes bofs_s
    for (int off = 1; off < 256; off <<= 1) {
        int add = (t >= off) ? sh[t - off] : 0;
        __syncthreads();
        sh[t] += add;
        __syncthreads();
    }
    int ex = sh[t] - v + bofs_s;
    if (i < N_NODES) {
        rowptr[i] = ex;
        cursor[i] = ex;
        float deg = 1.0f + (float)d.x * (1.0f / 16777216.0f);  // self loop + Σew
        dinv[i] = 1.0f / sqrtf(deg);
    }
    if (i == 0) rowptr[N_NODES] = N_EDGES;
}

// ---------------- fill CSR x4: csr[pos] = (src, norm) ----------------
__global__ __launch_bounds__(256) void k_fill(const int* __restrict__ src,
                                              const int* __restrict__ dst,
                                              const float* __restrict__ ew,
                                              const float* __restrict__ dinv,
                                              int* __restrict__ cursor,
                                              int2* __restrict__ csr) {
    int e4 = blockIdx.x * 256 + threadIdx.x;
    if (e4 >= N_EDGES / 4) return;
    int4 s4 = ((const int4*)src)[e4];
    int4 d4 = ((const int4*)dst)[e4];
    float4 w4 = ((const float4*)ew)[e4];
    {
        int pos = atomicAdd(&cursor[d4.x], 1);
        csr[pos] = make_int2(s4.x, __float_as_int(dinv[s4.x] * w4.x * dinv[d4.x]));
    }
    {
        int pos = atomicAdd(&cursor[d4.y], 1);
        csr[pos] = make_int2(s4.y, __float_as_int(dinv[s4.y] * w4.y * dinv[d4.y]));
    }
    {
        int pos = atomicAdd(&cursor[d4.z], 1);
        csr[pos] = make_int2(s4.z, __float_as_int(dinv[s4.z] * w4.z * dinv[d4.z]));
    }
    {
        int pos = atomicAdd(&cursor[d4.w], 1);
        csr[pos] = make_int2(s4.w, __float_as_int(dinv[s4.w] * w4.w * dinv[d4.w]));
    }
}

// ---------------- bf16 MFMA GEMM: tbf[M,128] = A[M,K] @ W[K,128], bf16 out ----------
// Block: 64x128 tile, 256 threads (4 waves 2x2: 32 rows x 64 cols each), BK=32.
// 782 blocks -> ~3/CU for memory-parallelism on the BW-bound emb gather.
// MODE 0: A row m = [ x[m,0:128] | emb[ids[m],0:1024] ]  (K=1152, fp32 -> bf16)
// MODE 1: A row m = Xb[m,0:128] (already-relu'd bf16)     (K=128)
template <int MODE>
__global__ __launch_bounds__(256) void k_gemm(const float* __restrict__ X,
                                              const unsigned short* __restrict__ Xb,
                                              const float* __restrict__ EMB,
                                              const int* __restrict__ ids,
                                              const unsigned short* __restrict__ Wt,
                                              unsigned short* __restrict__ tbf, int K) {
    __shared__ unsigned short As[64][40];   // [row][k], stride 40 (80 B)
    __shared__ unsigned short Bs[128][40];  // [col][k]

    const int tid = threadIdx.x;
    const int lane = tid & 63;
    const int wv = tid >> 6;
    const int wm = wv >> 1, wn = wv & 1;     // wave quadrant
    const int fr = lane & 15;                // frag row/col
    const int fq = lane >> 4;                // frag k-octet
    const int mBase = blockIdx.x * 64;

    // A staging: row = tid>>2 (0..63), 8 k at (tid&3)*8
    const int aRow = tid >> 2;
    const int aOff = (tid & 3) * 8;
    // B staging: col = tid>>1 (0..127), 16 k at (tid&1)*16
    const int bCol = tid >> 1;
    const int bOff = (tid & 1) * 16;

    const int m = mBase + aRow;
    const int mc = (m < N_NODES) ? m : (N_NODES - 1);
    int embRow = 0;
    if (MODE == 0) embRow = ids[mc];

    f32x4 acc[2][4];
#pragma unroll
    for (int i = 0; i < 2; i++)
#pragma unroll
        for (int j = 0; j < 4; j++) acc[i][j] = (f32x4){0.f, 0.f, 0.f, 0.f};

    // prefetch k0=0 globals
    float av[8];
    short8 axb;
    short8 bh0, bh1;
    {
        if (MODE == 0) {
            const float* aptr = X + (size_t)mc * N_FEAT + aOff;
            *(float4*)&av[0] = *(const float4*)(aptr);
            *(float4*)&av[4] = *(const float4*)(aptr + 4);
        } else {
            axb = *(const short8*)(Xb + (size_t)mc * HIDDEN + aOff);
        }
        size_t bo = (size_t)bCol * K + bOff;
        bh0 = *(const short8*)&Wt[bo];
        bh1 = *(const short8*)&Wt[bo + 8];
    }

    for (int k0 = 0; k0 < K; k0 += 32) {
        short8 ah;
        if (MODE == 0) {
#pragma unroll
            for (int i = 0; i < 8; i++) ah[i] = (short)f2bf(av[i]);
        } else {
            ah = axb;
        }
        *(short8*)&As[aRow][aOff] = ah;
        *(short8*)&Bs[bCol][bOff] = bh0;
        *(short8*)&Bs[bCol][bOff + 8] = bh1;
        __syncthreads();

        // prefetch next k-step globals (hidden behind MFMAs)
        int k1 = k0 + 32;
        if (k1 < K) {
            if (MODE == 0) {
                const float* aptr = (k1 < N_FEAT)
                    ? X + (size_t)mc * N_FEAT + k1 + aOff
                    : EMB + (size_t)embRow * EMB_DIM + (k1 - N_FEAT) + aOff;
                *(float4*)&av[0] = *(const float4*)(aptr);
                *(float4*)&av[4] = *(const float4*)(aptr + 4);
            } else {
                axb = *(const short8*)(Xb + (size_t)mc * HIDDEN + k1 + aOff);
            }
            size_t bo = (size_t)bCol * K + k1 + bOff;
            bh0 = *(const short8*)&Wt[bo];
            bh1 = *(const short8*)&Wt[bo + 8];
        }

        short8 aF[2], bF[4];
#pragma unroll
        for (int i = 0; i < 2; i++)
            aF[i] = *(const short8*)&As[wm * 32 + i * 16 + fr][fq * 8];
#pragma unroll
        for (int j = 0; j < 4; j++)
            bF[j] = *(const short8*)&Bs[wn * 64 + j * 16 + fr][fq * 8];

#pragma unroll
        for (int i = 0; i < 2; i++)
#pragma unroll
            for (int j = 0; j < 4; j++)
                acc[i][j] = __builtin_amdgcn_mfma_f32_16x16x32_bf16(aF[i], bF[j], acc[i][j], 0, 0, 0);
        __syncthreads();
    }

    // epilogue: C/D map col=lane&15, row=(lane>>4)*4+reg ; write bf16
#pragma unroll
    for (int i = 0; i < 2; i++) {
#pragma unroll
        for (int j = 0; j < 4; j++) {
            int gcol = wn * 64 + j * 16 + fr;
#pragma unroll
            for (int r = 0; r < 4; r++) {
                int grow = mBase + wm * 32 + i * 16 + fq * 4 + r;
                if (grow < N_NODES) tbf[(size_t)grow * HIDDEN + gcol] = f2bf(acc[i][j][r]);
            }
        }
    }
}

// ------------- CSR gather-aggregate: 16-lane GROUP per node (4 nodes/wave) ----------
// Each group owns its node end-to-end: no cross-group reduce; a node's gathers are
// independent -> 4-deep rounds, 16 gathers in flight per wave.
// acc[n,:] = sum_e norm_e * t[src_e,:] + dinv[n]^2 * t[n,:] + b ; then relu.
// POOL=0: write bf16 row (h1).  POOL=1: per-block LDS pool into sums/counts.
template <int POOL, int NWAVE>
__global__ __launch_bounds__(NWAVE * 64) void k_agg(const int2* __restrict__ csr,
                                                    const int* __restrict__ rowptr,
                                                    const float* __restrict__ dinv,
                                                    const unsigned short* __restrict__ tbf,
                                                    const float* __restrict__ bias,
                                                    const int* __restrict__ batch,
                                                    unsigned short* __restrict__ outb,
                                                    float* __restrict__ sums,
                                                    float* __restrict__ counts) {
    __shared__ float lsum[HIDDEN];
    __shared__ int lcnt;
    const int wv = threadIdx.x >> 6;
    const int lane = threadIdx.x & 63;
    const int g = lane >> 4;         // group 0..3
    const int q = lane & 15;         // col quad: cols q*8 .. q*8+7
    const int n = (blockIdx.x * NWAVE + wv) * 4 + g;
    const uint4* t128 = (const uint4*)tbf;   // row n = 16 uint4 at n*16

    if (POOL) {
        if (threadIdx.x < HIDDEN) lsum[threadIdx.x] = 0.f;
        if (threadIdx.x == 0) lcnt = 0;
        __syncthreads();
    }

    float acc[8] = {};
    if (n < N_NODES) {
        const int beg = rowptr[n];
        const int end = rowptr[n + 1];
        const float di = dinv[n];
        const float wself = di * di;
        uint4 sr = t128[(size_t)n * 16 + q];
        float4 b0 = ((const float4*)bias)[q * 2];
        float4 b1 = ((const float4*)bias)[q * 2 + 1];
        acc[0] = fmaf(wself, bflo(sr.x), b0.x); acc[1] = fmaf(wself, bfhi(sr.x), b0.y);
        acc[2] = fmaf(wself, bflo(sr.y), b0.z); acc[3] = fmaf(wself, bfhi(sr.y), b0.w);
        acc[4] = fmaf(wself, bflo(sr.z), b1.x); acc[5] = fmaf(wself, bfhi(sr.z), b1.y);
        acc[6] = fmaf(wself, bflo(sr.w), b1.z); acc[7] = fmaf(wself, bfhi(sr.w), b1.w);

        for (int base = beg; base < end; base += 16) {
            int cnt = end - base; if (cnt > 16) cnt = 16;
            int2 ce = (q < cnt) ? csr[base + q] : make_int2(0, 0);  // pad: w=0
            int rounds = (cnt + 3) >> 2;
            for (int rr = 0; rr < rounds; rr++) {
                int j0 = g * 16 + rr * 4;   // shfl source lanes within this group
                int   s0 = __shfl(ce.x, j0),     s1 = __shfl(ce.x, j0 + 1);
                int   s2 = __shfl(ce.x, j0 + 2), s3 = __shfl(ce.x, j0 + 3);
                float w0 = __int_as_float(__shfl(ce.y, j0));
                float w1 = __int_as_float(__shfl(ce.y, j0 + 1));
                float w2 = __int_as_float(__shfl(ce.y, j0 + 2));
                float w3 = __int_as_float(__shfl(ce.y, j0 + 3));
                uint4 r0 = t128[(size_t)s0 * 16 + q];
                uint4 r1 = t128[(size_t)s1 * 16 + q];
                uint4 r2 = t128[(size_t)s2 * 16 + q];
                uint4 r3 = t128[(size_t)s3 * 16 + q];
                acc[0] = fmaf(w0, bflo(r0.x), acc[0]); acc[1] = fmaf(w0, bfhi(r0.x), acc[1]);
                acc[2] = fmaf(w0, bflo(r0.y), acc[2]); acc[3] = fmaf(w0, bfhi(r0.y), acc[3]);
                acc[4] = fmaf(w0, bflo(r0.z), acc[4]); acc[5] = fmaf(w0, bfhi(r0.z), acc[5]);
                acc[6] = fmaf(w0, bflo(r0.w), acc[6]); acc[7] = fmaf(w0, bfhi(r0.w), acc[7]);
                acc[0] = fmaf(w1, bflo(r1.x), acc[0]); acc[1] = fmaf(w1, bfhi(r1.x), acc[1]);
                acc[2] = fmaf(w1, bflo(r1.y), acc[2]); acc[3] = fmaf(w1, bfhi(r1.y), acc[3]);
                acc[4] = fmaf(w1, bflo(r1.z), acc[4]); acc[5] = fmaf(w1, bfhi(r1.z), acc[5]);
                acc[6] = fmaf(w1, bflo(r1.w), acc[6]); acc[7] = fmaf(w1, bfhi(r1.w), acc[7]);
                acc[0] = fmaf(w2, bflo(r2.x), acc[0]); acc[1] = fmaf(w2, bfhi(r2.x), acc[1]);
                acc[2] = fmaf(w2, bflo(r2.y), acc[2]); acc[3] = fmaf(w2, bfhi(r2.y), acc[3]);
                acc[4] = fmaf(w2, bflo(r2.z), acc[4]); acc[5] = fmaf(w2, bfhi(r2.z), acc[5]);
                acc[6] = fmaf(w2, bflo(r2.w), acc[6]); acc[7] = fmaf(w2, bfhi(r2.w), acc[7]);
                acc[0] = fmaf(w3, bflo(r3.x), acc[0]); acc[1] = fmaf(w3, bfhi(r3.x), acc[1]);
                acc[2] = fmaf(w3, bflo(r3.y), acc[2]); acc[3] = fmaf(w3, bfhi(r3.y), acc[3]);
                acc[4] = fmaf(w3, bflo(r3.z), acc[4]); acc[5] = fmaf(w3, bfhi(r3.z), acc[5]);
                acc[6] = fmaf(w3, bflo(r3.w), acc[6]); acc[7] = fmaf(w3, bfhi(r3.w), acc[7]);
            }
        }
#pragma unroll
        for (int i = 0; i < 8; i++) acc[i] = fmaxf(acc[i], 0.f);  // relu
    }

    if (!POOL) {
        if (n < N_NODES) {
            uint4 o;
            o.x = packbf(acc[0], acc[1]);
            o.y = packbf(acc[2], acc[3]);
            o.z = packbf(acc[4], acc[5]);
            o.w = packbf(acc[6], acc[7]);
            ((uint4*)outb)[(size_t)n * 16 + q] = o;
        }
    } else {
        if (n < N_NODES) {
            int gn = batch[n];
            int g0 = batch[blockIdx.x * NWAVE * 4];  // block's leading graph
            if (gn == g0) {
#pragma unroll
                for (int i = 0; i < 8; i++) atomicAdd(&lsum[q * 8 + i], acc[i]);
                if (q == 0) atomicAdd(&lcnt, 1);
            } else {  // rare boundary node: direct global
#pragma unroll
                for (int i = 0; i < 8; i++) atomicAdd(&sums[gn * HIDDEN + q * 8 + i], acc[i]);
                if (q == 0) atomicAdd(&counts[gn], 1.0f);
            }
        }
        __syncthreads();
        int g0 = batch[blockIdx.x * NWAVE * 4];
        if (threadIdx.x < HIDDEN) atomicAdd(&sums[g0 * HIDDEN + threadIdx.x], lsum[threadIdx.x]);
        if (threadIdx.x == 0) atomicAdd(&counts[g0], (float)lcnt);
    }
}

// ---------------- final: out[g,o] = (sums[g,:]/max(cnt,1)) @ fcW + fcb -------------
__global__ __launch_bounds__(64) void k_final(const float* __restrict__ sums,
                                              const float* __restrict__ counts,
                                              const float* __restrict__ fcW,
                                              const float* __restrict__ fcb,
                                              float* __restrict__ out) {
    int g = blockIdx.x;
    int o = threadIdx.x;
    if (o >= OUT_DIM) return;
    float inv = 1.0f / fmaxf(counts[g], 1.0f);
    float acc = 0.f;
    for (int f = 0; f < HIDDEN; f++)
        acc = fmaf(sums[g * HIDDEN + f], fcW[f * OUT_DIM + o], acc);
    out[g * OUT_DIM + o] = acc * inv + fcb[o];
}

extern "C" void kernel_launch(void* const* d_in, const int* in_sizes, int n_in,
                              void* d_out, int out_size, void* d_ws, size_t ws_size,
                              hipStream_t stream) {
    const float* x      = (const float*)d_in[0];
    const float* ew     = (const float*)d_in[1];
    const float* emb    = (const float*)d_in[2];
    const float* W1     = (const float*)d_in[3];
    const float* b1     = (const float*)d_in[4];
    const float* W2     = (const float*)d_in[5];
    const float* b2     = (const float*)d_in[6];
    const float* fcW    = (const float*)d_in[7];
    const float* fcb    = (const float*)d_in[8];
    const int* edge_idx = (const int*)d_in[9];
    const int* batch    = (const int*)d_in[10];
    const int* node_ids = (const int*)d_in[11];
    float* out = (float*)d_out;

    const int* src = edge_idx;             // edge_index[0]
    const int* dst = edge_idx + N_EDGES;   // edge_index[1]

    // workspace layout (float units; bf16 buffers 16B-aligned)
    float* ws     = (float*)d_ws;
    float* dinv   = ws;                                        // 50048
    unsigned long long* dc = (unsigned long long*)(ws + 50048);// 50000 u64
    int*   cursor = (int*)(ws + 150048);                       // 50048
    int*   rowptr = (int*)(ws + 200096);                       // 50056
    int*   bsum   = (int*)(ws + 250152);                       // 256
    int2*  csr    = (int2*)(ws + 250408);                      // 500000 int2
    unsigned short* tbf   = (unsigned short*)(ws + 1250408);   // 6.4M bf16
    unsigned short* out1b = (unsigned short*)(ws + 4450408);   // 6.4M bf16 (h1)
    float* sums   = ws + 7650408;                              // 8192
    float* counts = sums + N_GRAPHS * HIDDEN;                  // 64
    unsigned short* wt1 = (unsigned short*)(ws + 7658664);     // 147456 bf16
    unsigned short* wt2 = (unsigned short*)(ws + 7732392);     // 16384 bf16

    const int NB_EDGE4 = (N_EDGES / 4 + 255) / 256;      // 489
    const int NB_GEMM  = (N_NODES + 63) / 64;            // 782
    const int K1 = N_FEAT + EMB_DIM;                     // 1152

    // preprocessing: init+prep fused (36 W1 blocks + 4 W2 blocks), packed degrees,
    // 2-kernel scan, CSR fill
    k_init <<<NB_NODE + 40, 256, 0, stream>>>(dc, sums, counts, W1, wt1, W2, wt2);
    k_deg  <<<NB_EDGE4, 256, 0, stream>>>(dst, ew, dc);
    k_scan1<<<NB_NODE, 256, 0, stream>>>(dc, bsum);
    k_scan3<<<NB_NODE, 256, 0, stream>>>(dc, bsum, cursor, rowptr, dinv);
    k_fill <<<NB_EDGE4, 256, 0, stream>>>(src, dst, ew, dinv, cursor, csr);

    // conv1: t1 = [x|emb] @ W1 (bf16) ; h1 = relu(aggregate + self + b1) (bf16)
    k_gemm<0><<<NB_GEMM, 256, 0, stream>>>(x, nullptr, emb, node_ids, wt1, tbf, K1);
    k_agg<0, 4><<<(N_NODES + 15) / 16, 256, 0, stream>>>(csr, rowptr, dinv, tbf, b1,
                                                         batch, out1b, sums, counts);

    // conv2: t2 = h1 @ W2 (bf16) ; fused aggregate+relu+pool
    k_gemm<1><<<NB_GEMM, 256, 0, stream>>>(nullptr, out1b, nullptr, nullptr, wt2, tbf, HIDDEN);
    k_agg<1, 16><<<(N_NODES + 63) / 64, 1024, 0, stream>>>(csr, rowptr, dinv, tbf, b2,
                                                           batch, nullptr, sums, counts);

    // classifier
    k_final<<<N_GRAPHS, 64, 0, stream>>>(sums, counts, fcW, fcb, out);
}